// Round 4
// baseline (972.982 us; speedup 1.0000x reference)
//
#include <hip/hip_runtime.h>

#define D 128
#define OUTD 384
#define SLOPE 0.2f
#define BSH 6                  // bucket = row >> 6  (64 rows/bucket)
#define BROWS 64
#define CAP 3072               // max edges per bucket held in LDS (avg ~2048, 20+ sigma margin)
#define MAXNB 2560

__device__ __forceinline__ unsigned f2bf(float f) {   // round-to-nearest-even bf16
    unsigned u = __float_as_uint(f);
    return (u + 0x7FFFu + ((u >> 16) & 1u)) >> 16;
}

// ---------------- copy raw embeddings into out cols [0,128) ----------------
__global__ __launch_bounds__(256) void copy_raw(const float* __restrict__ ue,
                                                const float* __restrict__ ie,
                                                float* __restrict__ out,
                                                int U, int N) {
    int idx = blockIdx.x * 256 + threadIdx.x;
    int total = N * (D / 4);
    if (idx >= total) return;
    int row = idx >> 5;
    int c4  = (idx & 31) * 4;
    const float* src = (row < U) ? &ue[(size_t)row * D] : &ie[(size_t)(row - U) * D];
    *(float4*)&out[(size_t)row * OUTD + c4] = *(const float4*)&src[c4];
}

// ---------------- dense GEMM: featb[r] = bf16( in[r*pitch] @ W ) ----------------
#define GR 64
__global__ __launch_bounds__(256) void gemm64(const float* __restrict__ in, int pitch,
                                              const float* __restrict__ W,
                                              unsigned short* __restrict__ featb,
                                              int nrows) {
    __shared__ float sIn[GR * D];    // 32 KB
    __shared__ float sW[64 * D];     // 32 KB
    int tid = threadIdx.x;
    int row0 = blockIdx.x * GR;
    int nr = min(GR, nrows - row0);

    for (int i = tid; i < nr * 32; i += 256) {
        int r = i >> 5, c = (i & 31) * 4;
        *(float4*)&sIn[r * D + c] = *(const float4*)&in[(size_t)(row0 + r) * pitch + c];
    }

    int cg = tid & 31;
    int rs = tid >> 5;
    int c4 = cg * 4;

    float4 acc[8];
#pragma unroll
    for (int j = 0; j < 8; ++j) acc[j] = make_float4(0.f, 0.f, 0.f, 0.f);

    for (int kh = 0; kh < 2; ++kh) {
        __syncthreads();
        for (int i = tid * 4; i < 64 * D; i += 256 * 4)
            *(float4*)&sW[i] = *(const float4*)&W[kh * 64 * D + i];
        __syncthreads();
#pragma unroll 4
        for (int k = 0; k < 64; ++k) {
            float4 w = *(float4*)&sW[k * D + c4];
#pragma unroll
            for (int j = 0; j < 8; ++j) {
                float av = sIn[(rs * 8 + j) * D + kh * 64 + k];
                acc[j].x += av * w.x;
                acc[j].y += av * w.y;
                acc[j].z += av * w.z;
                acc[j].w += av * w.w;
            }
        }
    }
#pragma unroll
    for (int j = 0; j < 8; ++j) {
        int r = rs * 8 + j;
        if (r < nr) {
            uint2 p;
            p.x = f2bf(acc[j].x) | (f2bf(acc[j].y) << 16);
            p.y = f2bf(acc[j].z) | (f2bf(acc[j].w) << 16);
            *(uint2*)&featb[(size_t)(row0 + r) * D + c4] = p;
        }
    }
}

// ================= bucketed CSR build =================
// bcount/bcursor are padded: one int per 64B line (index b*16)

__global__ __launch_bounds__(256) void bucket_hist(const int* __restrict__ rows,
                                                   int* __restrict__ bcount,
                                                   int nnz, int NB) {
    __shared__ int h[MAXNB];
    if (NB <= MAXNB) {
        for (int i = threadIdx.x; i < NB; i += 256) h[i] = 0;
        __syncthreads();
        int stride = gridDim.x * 256;
        for (int e = blockIdx.x * 256 + threadIdx.x; e < nnz; e += stride)
            atomicAdd(&h[rows[e] >> BSH], 1);
        __syncthreads();
        for (int i = threadIdx.x; i < NB; i += 256)
            if (h[i]) atomicAdd(&bcount[i * 16], h[i]);
    } else {
        int stride = gridDim.x * 256;
        for (int e = blockIdx.x * 256 + threadIdx.x; e < nnz; e += stride)
            atomicAdd(&bcount[(rows[e] >> BSH) * 16], 1);
    }
}

__global__ __launch_bounds__(256) void bucket_scan(const int* __restrict__ bcount,
                                                   int* __restrict__ bstart,
                                                   int* __restrict__ bcursor, int NB) {
    __shared__ int ps[257];
    int tid = threadIdx.x;
    int per = (NB + 255) / 256;
    int lo = tid * per, hi = min(lo + per, NB);
    int sum = 0;
    for (int i = lo; i < hi; ++i) sum += bcount[i * 16];
    ps[tid] = sum;
    __syncthreads();
    if (tid == 0) {
        int acc = 0;
        for (int i = 0; i < 256; ++i) { int t = ps[i]; ps[i] = acc; acc += t; }
        ps[256] = acc;
    }
    __syncthreads();
    int acc = ps[tid];
    for (int i = lo; i < hi; ++i) {
        int c = bcount[i * 16];
        bstart[i] = acc;
        bcursor[i * 16] = acc;
        acc += c;
    }
    if (tid == 255) bstart[NB] = ps[256];
}

// chunked scatter: each block owns a contiguous edge span; per-bucket LDS histogram,
// one chunk reservation atomic per (block,bucket), then contiguous chunk writes.
__global__ __launch_bounds__(256) void chunk_scatter(const int* __restrict__ rows,
                                                     const int* __restrict__ cols,
                                                     const float* __restrict__ vals,
                                                     int* __restrict__ bcursor,
                                                     uint2* __restrict__ epack,
                                                     int nnz, int NB) {
    __shared__ int hist[MAXNB];
    int tid  = threadIdx.x;
    int span = (nnz + gridDim.x - 1) / gridDim.x;
    int lo   = blockIdx.x * span;
    int hi   = min(lo + span, nnz);
    for (int i = tid; i < NB; i += 256) hist[i] = 0;
    __syncthreads();
    for (int e = lo + tid; e < hi; e += 256)
        atomicAdd(&hist[rows[e] >> BSH], 1);
    __syncthreads();
    for (int i = tid; i < NB; i += 256) {
        int c = hist[i];
        hist[i] = c ? atomicAdd(&bcursor[i * 16], c) : 0;   // chunk base -> LDS cursor
    }
    __syncthreads();
    for (int e = lo + tid; e < hi; e += 256) {
        int r = rows[e];
        int b = r >> BSH;
        int pos = atomicAdd(&hist[b], 1);
        uint2 p;
        p.x = ((unsigned)(r & (BROWS - 1)) << 18) | (unsigned)cols[e];
        p.y = __float_as_uint(vals[e]);
        epack[pos] = p;
    }
}

// per-bucket: LDS in-place row-sort of the region + emit row_start / rend
__global__ __launch_bounds__(256) void bucket_finalize(const int* __restrict__ bstart,
                                                       uint2* __restrict__ epack,
                                                       int* __restrict__ row_start,
                                                       int* __restrict__ rend,
                                                       int N) {
    __shared__ uint2 ed[CAP];
    __shared__ int rcnt[BROWS], rofs[BROWS];
    int b = blockIdx.x;
    int s = bstart[b];
    int len = bstart[b + 1] - s;
    if (len > CAP) len = CAP;   // statistically impossible; guards LDS
    int tid = threadIdx.x;
    if (tid < BROWS) rcnt[tid] = 0;
    __syncthreads();
    for (int i = tid; i < len; i += 256) {
        uint2 e = epack[s + i];
        ed[i] = e;
        atomicAdd(&rcnt[e.x >> 18], 1);
    }
    __syncthreads();
    if (tid < BROWS) {
        int c = rcnt[tid];
        int incl = c;
#pragma unroll
        for (int off = 1; off < BROWS; off <<= 1) {
            int t = __shfl_up(incl, off);
            if (tid >= off) incl += t;
        }
        int excl = incl - c;
        rofs[tid] = excl;
        int row = b * BROWS + tid;
        if (row < N) { row_start[row] = s + excl; rend[row] = s + excl + c; }
    }
    __syncthreads();
    for (int i = tid; i < len; i += 256) {
        uint2 e = ed[i];
        int rl = e.x >> 18;
        int pos = atomicAdd(&rofs[rl], 1);
        uint2 o; o.x = e.x & 0x3FFFFu; o.y = e.y;
        epack[s + pos] = o;
    }
}

// ================= CSR SpMM (bf16 gather): one wave per row, fused leaky (+opt norm) ===
__global__ __launch_bounds__(256) void spmm_csr(const uint2* __restrict__ ep,
                                                const int* __restrict__ rstart,
                                                const int* __restrict__ rend,
                                                const unsigned short* __restrict__ featb,
                                                float* __restrict__ out,
                                                int col_off, int N, int do_norm) {
    int row  = blockIdx.x * 4 + (threadIdx.x >> 6);
    int lane = threadIdx.x & 63;
    if (row >= N) return;
    int s = rstart[row], e = rend[row];
    float2 acc = {0.f, 0.f};
    int i = s;
    for (; i + 4 <= e; i += 4) {
        uint2 e0 = ep[i], e1 = ep[i + 1], e2 = ep[i + 2], e3 = ep[i + 3];
        unsigned g0 = *(const unsigned*)&featb[(size_t)e0.x * D + lane * 2];
        unsigned g1 = *(const unsigned*)&featb[(size_t)e1.x * D + lane * 2];
        unsigned g2 = *(const unsigned*)&featb[(size_t)e2.x * D + lane * 2];
        unsigned g3 = *(const unsigned*)&featb[(size_t)e3.x * D + lane * 2];
        float v0 = __uint_as_float(e0.y), v1 = __uint_as_float(e1.y);
        float v2 = __uint_as_float(e2.y), v3 = __uint_as_float(e3.y);
        acc.x += v0 * __uint_as_float(g0 << 16); acc.y += v0 * __uint_as_float(g0 & 0xFFFF0000u);
        acc.x += v1 * __uint_as_float(g1 << 16); acc.y += v1 * __uint_as_float(g1 & 0xFFFF0000u);
        acc.x += v2 * __uint_as_float(g2 << 16); acc.y += v2 * __uint_as_float(g2 & 0xFFFF0000u);
        acc.x += v3 * __uint_as_float(g3 << 16); acc.y += v3 * __uint_as_float(g3 & 0xFFFF0000u);
    }
    for (; i < e; ++i) {
        uint2 ev = ep[i];
        unsigned g = *(const unsigned*)&featb[(size_t)ev.x * D + lane * 2];
        float v = __uint_as_float(ev.y);
        acc.x += v * __uint_as_float(g << 16);
        acc.y += v * __uint_as_float(g & 0xFFFF0000u);
    }
    acc.x = (acc.x > 0.f) ? acc.x : SLOPE * acc.x;
    acc.y = (acc.y > 0.f) ? acc.y : SLOPE * acc.y;
    float* dst = &out[(size_t)row * OUTD + col_off + lane * 2];
    if (do_norm) {
        float ss = acc.x * acc.x + acc.y * acc.y;
#pragma unroll
        for (int m = 32; m >= 1; m >>= 1) ss += __shfl_xor(ss, m);
        float sc = 1.0f / fmaxf(sqrtf(ss), 1e-12f);
        float2 o = {acc.x * sc, acc.y * sc};
        *(float2*)dst = o;
    } else {
        float2 o = {acc.x, acc.y};
        *(float2*)dst = o;
    }
}

// normalize out cols [col_off, col_off+128) in place (values already leaky'd)
__global__ __launch_bounds__(256) void finalize_norm(float* __restrict__ out,
                                                     int col_off, int N) {
    int row  = blockIdx.x * 4 + (threadIdx.x >> 6);
    int lane = threadIdx.x & 63;
    if (row >= N) return;
    float* p = &out[(size_t)row * OUTD + col_off + lane * 2];
    float2 v = *(float2*)p;
    float ss = v.x * v.x + v.y * v.y;
#pragma unroll
    for (int m = 32; m >= 1; m >>= 1) ss += __shfl_xor(ss, m);
    float sc = 1.0f / fmaxf(sqrtf(ss), 1e-12f);
    float2 o = {v.x * sc, v.y * sc};
    *(float2*)p = o;
}

extern "C" void kernel_launch(void* const* d_in, const int* in_sizes, int n_in,
                              void* d_out, int out_size, void* d_ws, size_t ws_size,
                              hipStream_t stream) {
    const int*   rows = (const int*)d_in[0];
    const int*   cols = (const int*)d_in[1];
    const float* vals = (const float*)d_in[2];
    const float* ue   = (const float*)d_in[3];
    const float* ie   = (const float*)d_in[4];
    const float* uw0  = (const float*)d_in[5];
    const float* vw0  = (const float*)d_in[6];
    const float* uw1  = (const float*)d_in[7];
    const float* vw1  = (const float*)d_in[8];
    float* out = (float*)d_out;

    int nnz = in_sizes[0];
    int U   = in_sizes[3] / D;
    int I   = in_sizes[4] / D;
    int N   = U + I;
    int NB  = (N + BROWS - 1) >> BSH;

    // workspace layout
    char* p = (char*)d_ws;
    unsigned short* featb = (unsigned short*)p;  p += (size_t)N * D * 2;            // 38.4 MB
    uint2* epack          = (uint2*)p;           p += (size_t)nnz * 8;              // 38.4 MB
    int* row_start        = (int*)p;             p += (size_t)N * 4;
    int* rend             = (int*)p;             p += (size_t)N * 4;
    int* bstart           = (int*)p;             p += (size_t)(NB + 1) * 4;
    p = (char*)(((size_t)p + 63) & ~(size_t)63);
    int* bcount           = (int*)p;             p += (size_t)NB * 64;              // padded
    int* bcursor          = (int*)p;             p += (size_t)NB * 64;              // padded

    int vec_blocks = (N * (D / 4) + 255) / 256;
    int row_blocks = (N + 3) / 4;
    int gu = (U + GR - 1) / GR;
    int gi = (I + GR - 1) / GR;

    copy_raw<<<vec_blocks, 256, 0, stream>>>(ue, ie, out, U, N);

    // ---- build CSR (bucketed, chunked scatter) ----
    hipMemsetAsync(bcount, 0, (size_t)NB * 128, stream);   // bcount + bcursor contiguous
    bucket_hist<<<512, 256, 0, stream>>>(rows, bcount, nnz, NB);
    bucket_scan<<<1, 256, 0, stream>>>(bcount, bstart, bcursor, NB);
    chunk_scatter<<<128, 256, 0, stream>>>(rows, cols, vals, bcursor, epack, nnz, NB);
    bucket_finalize<<<NB, 256, 0, stream>>>(bstart, epack, row_start, rend, N);

    // ---- layer 0: gemm (bf16 out) -> spmm (leaky, unnormalized into out[128:256)) ----
    gemm64<<<gu, 256, 0, stream>>>(ue, D, uw0, featb, U);
    gemm64<<<gi, 256, 0, stream>>>(ie, D, vw0, featb + (size_t)U * D, I);
    spmm_csr<<<row_blocks, 256, 0, stream>>>(epack, row_start, rend, featb, out, D, N, 0);

    // ---- layer 1: gemm reads leaky from out (pitch 384); normalize cols after ----
    gemm64<<<gu, 256, 0, stream>>>(out + D, OUTD, uw1, featb, U);
    gemm64<<<gi, 256, 0, stream>>>(out + (size_t)U * OUTD + D, OUTD, vw1,
                                   featb + (size_t)U * D, I);
    finalize_norm<<<row_blocks, 256, 0, stream>>>(out, D, N);
    spmm_csr<<<row_blocks, 256, 0, stream>>>(epack, row_start, rend, featb, out, 2 * D, N, 1);
}

// Round 5
// 829.062 us; speedup vs baseline: 1.1736x; 1.1736x over previous
//
#include <hip/hip_runtime.h>

#define D 128
#define OUTD 384
#define SLOPE 0.2f
#define BSH 8                  // bucket = row >> 8  (256 rows/bucket)
#define BROWS 256
#define MAXNB 1024

__device__ __forceinline__ unsigned f2bf(float f) {   // round-to-nearest-even bf16
    unsigned u = __float_as_uint(f);
    return (u + 0x7FFFu + ((u >> 16) & 1u)) >> 16;
}

// ---------------- copy raw embeddings into out cols [0,128) ----------------
__global__ __launch_bounds__(256) void copy_raw(const float* __restrict__ ue,
                                                const float* __restrict__ ie,
                                                float* __restrict__ out,
                                                int U, int N) {
    int idx = blockIdx.x * 256 + threadIdx.x;
    int total = N * (D / 4);
    if (idx >= total) return;
    int row = idx >> 5;
    int c4  = (idx & 31) * 4;
    const float* src = (row < U) ? &ue[(size_t)row * D] : &ie[(size_t)(row - U) * D];
    *(float4*)&out[(size_t)row * OUTD + c4] = *(const float4*)&src[c4];
}

// ---------------- dense GEMM: featb[r] = bf16( in[r*pitch] @ W ) ----------------
#define GR 64
__global__ __launch_bounds__(256) void gemm64(const float* __restrict__ in, int pitch,
                                              const float* __restrict__ W,
                                              unsigned short* __restrict__ featb,
                                              int nrows) {
    __shared__ float sIn[GR * D];    // 32 KB
    __shared__ float sW[64 * D];     // 32 KB
    int tid = threadIdx.x;
    int row0 = blockIdx.x * GR;
    int nr = min(GR, nrows - row0);

    for (int i = tid; i < nr * 32; i += 256) {
        int r = i >> 5, c = (i & 31) * 4;
        *(float4*)&sIn[r * D + c] = *(const float4*)&in[(size_t)(row0 + r) * pitch + c];
    }

    int cg = tid & 31;
    int rs = tid >> 5;
    int c4 = cg * 4;

    float4 acc[8];
#pragma unroll
    for (int j = 0; j < 8; ++j) acc[j] = make_float4(0.f, 0.f, 0.f, 0.f);

    for (int kh = 0; kh < 2; ++kh) {
        __syncthreads();
        for (int i = tid * 4; i < 64 * D; i += 256 * 4)
            *(float4*)&sW[i] = *(const float4*)&W[kh * 64 * D + i];
        __syncthreads();
#pragma unroll 4
        for (int k = 0; k < 64; ++k) {
            float4 w = *(float4*)&sW[k * D + c4];
#pragma unroll
            for (int j = 0; j < 8; ++j) {
                float av = sIn[(rs * 8 + j) * D + kh * 64 + k];
                acc[j].x += av * w.x;
                acc[j].y += av * w.y;
                acc[j].z += av * w.z;
                acc[j].w += av * w.w;
            }
        }
    }
#pragma unroll
    for (int j = 0; j < 8; ++j) {
        int r = rs * 8 + j;
        if (r < nr) {
            uint2 p;
            p.x = f2bf(acc[j].x) | (f2bf(acc[j].y) << 16);
            p.y = f2bf(acc[j].z) | (f2bf(acc[j].w) << 16);
            *(uint2*)&featb[(size_t)(row0 + r) * D + c4] = p;
        }
    }
}

// ================= bucketed CSR build =================
// bcount/bcursor are padded: one int per 64B line (index b*16)

__global__ __launch_bounds__(256) void bucket_hist(const int* __restrict__ rows,
                                                   int* __restrict__ bcount,
                                                   int nnz, int NB) {
    __shared__ int h[MAXNB];
    if (NB <= MAXNB) {
        for (int i = threadIdx.x; i < NB; i += 256) h[i] = 0;
        __syncthreads();
        int stride = gridDim.x * 256;
        for (int e = blockIdx.x * 256 + threadIdx.x; e < nnz; e += stride)
            atomicAdd(&h[rows[e] >> BSH], 1);
        __syncthreads();
        for (int i = threadIdx.x; i < NB; i += 256)
            if (h[i]) atomicAdd(&bcount[i * 16], h[i]);
    } else {
        int stride = gridDim.x * 256;
        for (int e = blockIdx.x * 256 + threadIdx.x; e < nnz; e += stride)
            atomicAdd(&bcount[(rows[e] >> BSH) * 16], 1);
    }
}

__global__ __launch_bounds__(256) void bucket_scan(const int* __restrict__ bcount,
                                                   int* __restrict__ bstart,
                                                   int* __restrict__ bcursor, int NB) {
    __shared__ int ps[257];
    int tid = threadIdx.x;
    int per = (NB + 255) / 256;
    int lo = tid * per, hi = min(lo + per, NB);
    int sum = 0;
    for (int i = lo; i < hi; ++i) sum += bcount[i * 16];
    ps[tid] = sum;
    __syncthreads();
    if (tid == 0) {
        int acc = 0;
        for (int i = 0; i < 256; ++i) { int t = ps[i]; ps[i] = acc; acc += t; }
        ps[256] = acc;
    }
    __syncthreads();
    int acc = ps[tid];
    for (int i = lo; i < hi; ++i) {
        int c = bcount[i * 16];
        bstart[i] = acc;
        bcursor[i * 16] = acc;
        acc += c;
    }
    if (tid == 255) bstart[NB] = ps[256];
}

// chunked scatter: each block owns a contiguous edge span; per-bucket LDS histogram,
// one chunk reservation atomic per (block,bucket), then contiguous chunk writes.
// Writes bucket-grouped (row-unsorted) edges into etmp.
__global__ __launch_bounds__(256) void chunk_scatter(const int* __restrict__ rows,
                                                     const int* __restrict__ cols,
                                                     const float* __restrict__ vals,
                                                     int* __restrict__ bcursor,
                                                     uint2* __restrict__ etmp,
                                                     int nnz, int NB) {
    __shared__ int hist[MAXNB];
    int tid  = threadIdx.x;
    int span = (nnz + gridDim.x - 1) / gridDim.x;
    int lo   = blockIdx.x * span;
    int hi   = min(lo + span, nnz);
    if (NB <= MAXNB) {
        for (int i = tid; i < NB; i += 256) hist[i] = 0;
        __syncthreads();
        for (int e = lo + tid; e < hi; e += 256)
            atomicAdd(&hist[rows[e] >> BSH], 1);
        __syncthreads();
        for (int i = tid; i < NB; i += 256) {
            int c = hist[i];
            hist[i] = c ? atomicAdd(&bcursor[i * 16], c) : 0;   // chunk base
        }
        __syncthreads();
        for (int e = lo + tid; e < hi; e += 256) {
            int r = rows[e];
            int b = r >> BSH;
            int pos = atomicAdd(&hist[b], 1);
            uint2 p;
            p.x = ((unsigned)(r & (BROWS - 1)) << 18) | (unsigned)cols[e];
            p.y = __float_as_uint(vals[e]);
            etmp[pos] = p;
        }
    } else {
        for (int e = lo + tid; e < hi; e += 256) {
            int r = rows[e];
            int b = r >> BSH;
            int pos = atomicAdd(&bcursor[b * 16], 1);
            uint2 p;
            p.x = ((unsigned)(r & (BROWS - 1)) << 18) | (unsigned)cols[e];
            p.y = __float_as_uint(vals[e]);
            etmp[pos] = p;
        }
    }
}

// per-bucket two-pass row sort: etmp (bucket-grouped) -> epack (row-sorted),
// emits row_start / rend. No edge staging in LDS -> no capacity limit.
__global__ __launch_bounds__(256) void bucket_sort2(const int* __restrict__ bstart,
                                                    const uint2* __restrict__ etmp,
                                                    uint2* __restrict__ epack,
                                                    int* __restrict__ row_start,
                                                    int* __restrict__ rend,
                                                    int N) {
    __shared__ int rcnt[BROWS];
    __shared__ int rbase[BROWS];
    __shared__ int wsum[4];
    int b   = blockIdx.x;
    int s   = bstart[b];
    int len = bstart[b + 1] - s;
    int tid = threadIdx.x;
    rcnt[tid] = 0;
    __syncthreads();
    for (int i = tid; i < len; i += 256)
        atomicAdd(&rcnt[etmp[s + i].x >> 18], 1);
    __syncthreads();
    int c = rcnt[tid];
    int lane = tid & 63, wid = tid >> 6;
    int incl = c;
#pragma unroll
    for (int off = 1; off < 64; off <<= 1) {
        int t = __shfl_up(incl, off);
        if (lane >= off) incl += t;
    }
    if (lane == 63) wsum[wid] = incl;
    __syncthreads();
    int woff = 0;
    for (int w = 0; w < wid; ++w) woff += wsum[w];
    int excl = woff + incl - c;
    rbase[tid] = s + excl;
    int row = b * BROWS + tid;
    if (row < N) { row_start[row] = s + excl; rend[row] = s + excl + c; }
    __syncthreads();
    for (int i = tid; i < len; i += 256) {
        uint2 e = etmp[s + i];
        int rl = e.x >> 18;
        int pos = atomicAdd(&rbase[rl], 1);
        uint2 o; o.x = e.x & 0x3FFFFu; o.y = e.y;
        epack[pos] = o;
    }
}

// ================= CSR SpMM (bf16 gather): one wave per row, fused leaky (+opt norm) ===
__global__ __launch_bounds__(256) void spmm_csr(const uint2* __restrict__ ep,
                                                const int* __restrict__ rstart,
                                                const int* __restrict__ rend,
                                                const unsigned short* __restrict__ featb,
                                                float* __restrict__ out,
                                                int col_off, int N, int do_norm) {
    int row  = blockIdx.x * 4 + (threadIdx.x >> 6);
    int lane = threadIdx.x & 63;
    if (row >= N) return;
    int s = rstart[row], e = rend[row];
    float2 acc = {0.f, 0.f};
    int i = s;
    for (; i + 4 <= e; i += 4) {
        uint2 e0 = ep[i], e1 = ep[i + 1], e2 = ep[i + 2], e3 = ep[i + 3];
        unsigned g0 = *(const unsigned*)&featb[(size_t)e0.x * D + lane * 2];
        unsigned g1 = *(const unsigned*)&featb[(size_t)e1.x * D + lane * 2];
        unsigned g2 = *(const unsigned*)&featb[(size_t)e2.x * D + lane * 2];
        unsigned g3 = *(const unsigned*)&featb[(size_t)e3.x * D + lane * 2];
        float v0 = __uint_as_float(e0.y), v1 = __uint_as_float(e1.y);
        float v2 = __uint_as_float(e2.y), v3 = __uint_as_float(e3.y);
        acc.x += v0 * __uint_as_float(g0 << 16); acc.y += v0 * __uint_as_float(g0 & 0xFFFF0000u);
        acc.x += v1 * __uint_as_float(g1 << 16); acc.y += v1 * __uint_as_float(g1 & 0xFFFF0000u);
        acc.x += v2 * __uint_as_float(g2 << 16); acc.y += v2 * __uint_as_float(g2 & 0xFFFF0000u);
        acc.x += v3 * __uint_as_float(g3 << 16); acc.y += v3 * __uint_as_float(g3 & 0xFFFF0000u);
    }
    for (; i < e; ++i) {
        uint2 ev = ep[i];
        unsigned g = *(const unsigned*)&featb[(size_t)ev.x * D + lane * 2];
        float v = __uint_as_float(ev.y);
        acc.x += v * __uint_as_float(g << 16);
        acc.y += v * __uint_as_float(g & 0xFFFF0000u);
    }
    acc.x = (acc.x > 0.f) ? acc.x : SLOPE * acc.x;
    acc.y = (acc.y > 0.f) ? acc.y : SLOPE * acc.y;
    float* dst = &out[(size_t)row * OUTD + col_off + lane * 2];
    if (do_norm) {
        float ss = acc.x * acc.x + acc.y * acc.y;
#pragma unroll
        for (int m = 32; m >= 1; m >>= 1) ss += __shfl_xor(ss, m);
        float sc = 1.0f / fmaxf(sqrtf(ss), 1e-12f);
        float2 o = {acc.x * sc, acc.y * sc};
        *(float2*)dst = o;
    } else {
        float2 o = {acc.x, acc.y};
        *(float2*)dst = o;
    }
}

// normalize out cols [col_off, col_off+128) in place (values already leaky'd)
__global__ __launch_bounds__(256) void finalize_norm(float* __restrict__ out,
                                                     int col_off, int N) {
    int row  = blockIdx.x * 4 + (threadIdx.x >> 6);
    int lane = threadIdx.x & 63;
    if (row >= N) return;
    float* p = &out[(size_t)row * OUTD + col_off + lane * 2];
    float2 v = *(float2*)p;
    float ss = v.x * v.x + v.y * v.y;
#pragma unroll
    for (int m = 32; m >= 1; m >>= 1) ss += __shfl_xor(ss, m);
    float sc = 1.0f / fmaxf(sqrtf(ss), 1e-12f);
    float2 o = {v.x * sc, v.y * sc};
    *(float2*)p = o;
}

extern "C" void kernel_launch(void* const* d_in, const int* in_sizes, int n_in,
                              void* d_out, int out_size, void* d_ws, size_t ws_size,
                              hipStream_t stream) {
    const int*   rows = (const int*)d_in[0];
    const int*   cols = (const int*)d_in[1];
    const float* vals = (const float*)d_in[2];
    const float* ue   = (const float*)d_in[3];
    const float* ie   = (const float*)d_in[4];
    const float* uw0  = (const float*)d_in[5];
    const float* vw0  = (const float*)d_in[6];
    const float* uw1  = (const float*)d_in[7];
    const float* vw1  = (const float*)d_in[8];
    float* out = (float*)d_out;

    int nnz = in_sizes[0];
    int U   = in_sizes[3] / D;
    int I   = in_sizes[4] / D;
    int N   = U + I;
    int NB  = (N + BROWS - 1) >> BSH;

    // workspace layout
    char* p = (char*)d_ws;
    unsigned short* featb = (unsigned short*)p;  p += (size_t)N * D * 2;            // 38.4 MB
    uint2* epack          = (uint2*)p;           p += (size_t)nnz * 8;              // 38.4 MB
    int* row_start        = (int*)p;             p += (size_t)N * 4;
    int* rend             = (int*)p;             p += (size_t)N * 4;
    int* bstart           = (int*)p;             p += (size_t)(NB + 1) * 4;
    p = (char*)(((size_t)p + 63) & ~(size_t)63);
    int* bcount           = (int*)p;             p += (size_t)NB * 64;              // padded
    int* bcursor          = (int*)p;             p += (size_t)NB * 64;              // padded

    // temp bucket-grouped edges: reuse featb's space (dead until gemms run).
    // nnz*8 <= N*D*2 holds for this problem (4.8M*8 == 150K*256); else carve tail.
    uint2* etmp;
    if ((size_t)nnz * 8 <= (size_t)N * D * 2) {
        etmp = (uint2*)featb;
    } else {
        etmp = (uint2*)p;   // trust ws headroom in the unexpected case
    }

    int vec_blocks = (N * (D / 4) + 255) / 256;
    int row_blocks = (N + 3) / 4;
    int gu = (U + GR - 1) / GR;
    int gi = (I + GR - 1) / GR;

    copy_raw<<<vec_blocks, 256, 0, stream>>>(ue, ie, out, U, N);

    // ---- build CSR (bucketed, chunked scatter -> per-bucket 2-pass sort) ----
    hipMemsetAsync(bcount, 0, (size_t)NB * 128, stream);   // bcount + bcursor contiguous
    bucket_hist<<<512, 256, 0, stream>>>(rows, bcount, nnz, NB);
    bucket_scan<<<1, 256, 0, stream>>>(bcount, bstart, bcursor, NB);
    chunk_scatter<<<512, 256, 0, stream>>>(rows, cols, vals, bcursor, etmp, nnz, NB);
    bucket_sort2<<<NB, 256, 0, stream>>>(bstart, etmp, epack, row_start, rend, N);

    // ---- layer 0: gemm (bf16 out) -> spmm (leaky, unnormalized into out[128:256)) ----
    gemm64<<<gu, 256, 0, stream>>>(ue, D, uw0, featb, U);
    gemm64<<<gi, 256, 0, stream>>>(ie, D, vw0, featb + (size_t)U * D, I);
    spmm_csr<<<row_blocks, 256, 0, stream>>>(epack, row_start, rend, featb, out, D, N, 0);

    // ---- layer 1: gemm reads leaky from out (pitch 384); normalize cols after ----
    gemm64<<<gu, 256, 0, stream>>>(out + D, OUTD, uw1, featb, U);
    gemm64<<<gi, 256, 0, stream>>>(out + (size_t)U * OUTD + D, OUTD, vw1,
                                   featb + (size_t)U * D, I);
    finalize_norm<<<row_blocks, 256, 0, stream>>>(out, D, N);
    spmm_csr<<<row_blocks, 256, 0, stream>>>(epack, row_start, rend, featb, out, 2 * D, N, 1);
}

// Round 6
// 790.190 us; speedup vs baseline: 1.2313x; 1.0492x over previous
//
#include <hip/hip_runtime.h>

#define D 128
#define OUTD 384
#define SLOPE 0.2f
#define BSH 8                  // bucket = row >> 8  (256 rows/bucket)
#define BROWS 256
#define MAXNB 1024

__device__ __forceinline__ unsigned f2bf(float f) {   // round-to-nearest-even bf16
    unsigned u = __float_as_uint(f);
    return (u + 0x7FFFu + ((u >> 16) & 1u)) >> 16;
}

// ---------------- copy raw embeddings into out cols [0,128) ----------------
__global__ __launch_bounds__(256) void copy_raw(const float* __restrict__ ue,
                                                const float* __restrict__ ie,
                                                float* __restrict__ out,
                                                int U, int N) {
    int idx = blockIdx.x * 256 + threadIdx.x;
    int total = N * (D / 4);
    if (idx >= total) return;
    int row = idx >> 5;
    int c4  = (idx & 31) * 4;
    const float* src = (row < U) ? &ue[(size_t)row * D] : &ie[(size_t)(row - U) * D];
    *(float4*)&out[(size_t)row * OUTD + c4] = *(const float4*)&src[c4];
}

// ---------------- dense GEMM: featb[r] = bf16( (rowscale[r] * in[r*pitch]) @ W ) ----------
#define GR 64
__global__ __launch_bounds__(256) void gemm64(const float* __restrict__ in, int pitch,
                                              const float* __restrict__ W,
                                              unsigned short* __restrict__ featb,
                                              const float* __restrict__ rowscale,
                                              int nrows) {
    __shared__ float sIn[GR * D];    // 32 KB
    __shared__ float sW[64 * D];     // 32 KB
    int tid = threadIdx.x;
    int row0 = blockIdx.x * GR;
    int nr = min(GR, nrows - row0);

    for (int i = tid; i < nr * 32; i += 256) {
        int r = i >> 5, c = (i & 31) * 4;
        float4 t = *(const float4*)&in[(size_t)(row0 + r) * pitch + c];
        if (rowscale) {
            float s = rowscale[row0 + r];
            t.x *= s; t.y *= s; t.z *= s; t.w *= s;
        }
        *(float4*)&sIn[r * D + c] = t;
    }

    int cg = tid & 31;
    int rs = tid >> 5;
    int c4 = cg * 4;

    float4 acc[8];
#pragma unroll
    for (int j = 0; j < 8; ++j) acc[j] = make_float4(0.f, 0.f, 0.f, 0.f);

    for (int kh = 0; kh < 2; ++kh) {
        __syncthreads();
        for (int i = tid * 4; i < 64 * D; i += 256 * 4)
            *(float4*)&sW[i] = *(const float4*)&W[kh * 64 * D + i];
        __syncthreads();
#pragma unroll 4
        for (int k = 0; k < 64; ++k) {
            float4 w = *(float4*)&sW[k * D + c4];
#pragma unroll
            for (int j = 0; j < 8; ++j) {
                float av = sIn[(rs * 8 + j) * D + kh * 64 + k];
                acc[j].x += av * w.x;
                acc[j].y += av * w.y;
                acc[j].z += av * w.z;
                acc[j].w += av * w.w;
            }
        }
    }
#pragma unroll
    for (int j = 0; j < 8; ++j) {
        int r = rs * 8 + j;
        if (r < nr) {
            uint2 p;
            p.x = f2bf(acc[j].x) | (f2bf(acc[j].y) << 16);
            p.y = f2bf(acc[j].z) | (f2bf(acc[j].w) << 16);
            *(uint2*)&featb[(size_t)(row0 + r) * D + c4] = p;
        }
    }
}

// ================= bucketed CSR build =================
// bcount/bcursor are padded: one int per 64B line (index b*16)

__global__ __launch_bounds__(256) void bucket_hist(const int* __restrict__ rows,
                                                   int* __restrict__ bcount,
                                                   int nnz, int NB) {
    __shared__ int h[MAXNB];
    if (NB <= MAXNB) {
        for (int i = threadIdx.x; i < NB; i += 256) h[i] = 0;
        __syncthreads();
        int stride = gridDim.x * 256;
        for (int e = blockIdx.x * 256 + threadIdx.x; e < nnz; e += stride)
            atomicAdd(&h[rows[e] >> BSH], 1);
        __syncthreads();
        for (int i = threadIdx.x; i < NB; i += 256)
            if (h[i]) atomicAdd(&bcount[i * 16], h[i]);
    } else {
        int stride = gridDim.x * 256;
        for (int e = blockIdx.x * 256 + threadIdx.x; e < nnz; e += stride)
            atomicAdd(&bcount[(rows[e] >> BSH) * 16], 1);
    }
}

__global__ __launch_bounds__(256) void bucket_scan(const int* __restrict__ bcount,
                                                   int* __restrict__ bstart,
                                                   int* __restrict__ bcursor, int NB) {
    __shared__ int ps[257];
    int tid = threadIdx.x;
    int per = (NB + 255) / 256;
    int lo = tid * per, hi = min(lo + per, NB);
    int sum = 0;
    for (int i = lo; i < hi; ++i) sum += bcount[i * 16];
    ps[tid] = sum;
    __syncthreads();
    if (tid == 0) {
        int acc = 0;
        for (int i = 0; i < 256; ++i) { int t = ps[i]; ps[i] = acc; acc += t; }
        ps[256] = acc;
    }
    __syncthreads();
    int acc = ps[tid];
    for (int i = lo; i < hi; ++i) {
        int c = bcount[i * 16];
        bstart[i] = acc;
        bcursor[i * 16] = acc;
        acc += c;
    }
    if (tid == 255) bstart[NB] = ps[256];
}

// chunked scatter: each block owns a contiguous edge span; per-bucket LDS histogram,
// one chunk reservation atomic per (block,bucket), then contiguous chunk writes.
__global__ __launch_bounds__(256) void chunk_scatter(const int* __restrict__ rows,
                                                     const int* __restrict__ cols,
                                                     const float* __restrict__ vals,
                                                     int* __restrict__ bcursor,
                                                     uint2* __restrict__ etmp,
                                                     int nnz, int NB) {
    __shared__ int hist[MAXNB];
    int tid  = threadIdx.x;
    int span = (nnz + gridDim.x - 1) / gridDim.x;
    int lo   = blockIdx.x * span;
    int hi   = min(lo + span, nnz);
    if (NB <= MAXNB) {
        for (int i = tid; i < NB; i += 256) hist[i] = 0;
        __syncthreads();
        for (int e = lo + tid; e < hi; e += 256)
            atomicAdd(&hist[rows[e] >> BSH], 1);
        __syncthreads();
        for (int i = tid; i < NB; i += 256) {
            int c = hist[i];
            hist[i] = c ? atomicAdd(&bcursor[i * 16], c) : 0;   // chunk base
        }
        __syncthreads();
        for (int e = lo + tid; e < hi; e += 256) {
            int r = rows[e];
            int b = r >> BSH;
            int pos = atomicAdd(&hist[b], 1);
            uint2 p;
            p.x = ((unsigned)(r & (BROWS - 1)) << 18) | (unsigned)cols[e];
            p.y = __float_as_uint(vals[e]);
            etmp[pos] = p;
        }
    } else {
        for (int e = lo + tid; e < hi; e += 256) {
            int r = rows[e];
            int b = r >> BSH;
            int pos = atomicAdd(&bcursor[b * 16], 1);
            uint2 p;
            p.x = ((unsigned)(r & (BROWS - 1)) << 18) | (unsigned)cols[e];
            p.y = __float_as_uint(vals[e]);
            etmp[pos] = p;
        }
    }
}

// per-bucket two-pass row sort: etmp (bucket-grouped) -> epack (row-sorted),
// emits row_start / rend.
__global__ __launch_bounds__(256) void bucket_sort2(const int* __restrict__ bstart,
                                                    const uint2* __restrict__ etmp,
                                                    uint2* __restrict__ epack,
                                                    int* __restrict__ row_start,
                                                    int* __restrict__ rend,
                                                    int N) {
    __shared__ int rcnt[BROWS];
    __shared__ int rbase[BROWS];
    __shared__ int wsum[4];
    int b   = blockIdx.x;
    int s   = bstart[b];
    int len = bstart[b + 1] - s;
    int tid = threadIdx.x;
    rcnt[tid] = 0;
    __syncthreads();
    for (int i = tid; i < len; i += 256)
        atomicAdd(&rcnt[etmp[s + i].x >> 18], 1);
    __syncthreads();
    int c = rcnt[tid];
    int lane = tid & 63, wid = tid >> 6;
    int incl = c;
#pragma unroll
    for (int off = 1; off < 64; off <<= 1) {
        int t = __shfl_up(incl, off);
        if (lane >= off) incl += t;
    }
    if (lane == 63) wsum[wid] = incl;
    __syncthreads();
    int woff = 0;
    for (int w = 0; w < wid; ++w) woff += wsum[w];
    int excl = woff + incl - c;
    rbase[tid] = s + excl;
    int row = b * BROWS + tid;
    if (row < N) { row_start[row] = s + excl; rend[row] = s + excl + c; }
    __syncthreads();
    for (int i = tid; i < len; i += 256) {
        uint2 e = etmp[s + i];
        int rl = e.x >> 18;
        int pos = atomicAdd(&rbase[rl], 1);
        uint2 o; o.x = e.x & 0x3FFFFu; o.y = e.y;
        epack[pos] = o;
    }
}

// ================= CSR SpMM v2: wave per row, 2 edges per gather instruction ==========
// Lane j of half h (h = lane>>5) loads 8 B (4 bf16) of edge i+h's feature row.
// Fused leaky + L2-norm; optionally saves row norm for unnorm reconstruction.
#define ACC4(vbits, g)                                            \
    {                                                             \
        float v = __uint_as_float(vbits);                         \
        acc.x += v * __uint_as_float((g).x << 16);                \
        acc.y += v * __uint_as_float((g).x & 0xFFFF0000u);        \
        acc.z += v * __uint_as_float((g).y << 16);                \
        acc.w += v * __uint_as_float((g).y & 0xFFFF0000u);        \
    }

__global__ __launch_bounds__(256) void spmm_csr2(const uint2* __restrict__ ep,
                                                 const int* __restrict__ rstart,
                                                 const int* __restrict__ rend,
                                                 const unsigned short* __restrict__ featb,
                                                 float* __restrict__ out,
                                                 float* __restrict__ nsave,
                                                 int col_off, int N) {
    int row  = blockIdx.x * 4 + (threadIdx.x >> 6);
    if (row >= N) return;
    int lane = threadIdx.x & 63;
    int j = lane & 31;      // 4-element column group within the row
    int h = lane >> 5;      // which edge of the pair
    int s = rstart[row], e = rend[row];

    float4 acc = {0.f, 0.f, 0.f, 0.f};
    int i = s;
    for (; i + 8 <= e; i += 8) {
        uint2 e0 = ep[i + h];
        uint2 e1 = ep[i + 2 + h];
        uint2 e2 = ep[i + 4 + h];
        uint2 e3 = ep[i + 6 + h];
        uint2 g0 = *(const uint2*)&featb[(size_t)e0.x * D + j * 4];
        uint2 g1 = *(const uint2*)&featb[(size_t)e1.x * D + j * 4];
        uint2 g2 = *(const uint2*)&featb[(size_t)e2.x * D + j * 4];
        uint2 g3 = *(const uint2*)&featb[(size_t)e3.x * D + j * 4];
        ACC4(e0.y, g0);
        ACC4(e1.y, g1);
        ACC4(e2.y, g2);
        ACC4(e3.y, g3);
    }
    for (; i < e; i += 2) {
        int idx = i + h;
        uint2 ev = make_uint2(0u, 0u);          // col 0 / val 0: harmless dummy
        if (idx < e) ev = ep[idx];
        uint2 g = *(const uint2*)&featb[(size_t)ev.x * D + j * 4];
        ACC4(ev.y, g);
    }

    // combine the two halves
    acc.x += __shfl_xor(acc.x, 32);
    acc.y += __shfl_xor(acc.y, 32);
    acc.z += __shfl_xor(acc.z, 32);
    acc.w += __shfl_xor(acc.w, 32);

    // leaky relu
    acc.x = (acc.x > 0.f) ? acc.x : SLOPE * acc.x;
    acc.y = (acc.y > 0.f) ? acc.y : SLOPE * acc.y;
    acc.z = (acc.z > 0.f) ? acc.z : SLOPE * acc.z;
    acc.w = (acc.w > 0.f) ? acc.w : SLOPE * acc.w;

    // L2 norm over the 128 cols (each 32-lane half holds the full row)
    float ss = acc.x * acc.x + acc.y * acc.y + acc.z * acc.z + acc.w * acc.w;
#pragma unroll
    for (int m = 16; m >= 1; m >>= 1) ss += __shfl_xor(ss, m);
    float nm = fmaxf(sqrtf(ss), 1e-12f);
    float sc = 1.0f / nm;

    if (nsave && lane == 0) nsave[row] = nm;
    if (h == 0) {
        float4 o = {acc.x * sc, acc.y * sc, acc.z * sc, acc.w * sc};
        *(float4*)&out[(size_t)row * OUTD + col_off + j * 4] = o;
    }
}

extern "C" void kernel_launch(void* const* d_in, const int* in_sizes, int n_in,
                              void* d_out, int out_size, void* d_ws, size_t ws_size,
                              hipStream_t stream) {
    const int*   rows = (const int*)d_in[0];
    const int*   cols = (const int*)d_in[1];
    const float* vals = (const float*)d_in[2];
    const float* ue   = (const float*)d_in[3];
    const float* ie   = (const float*)d_in[4];
    const float* uw0  = (const float*)d_in[5];
    const float* vw0  = (const float*)d_in[6];
    const float* uw1  = (const float*)d_in[7];
    const float* vw1  = (const float*)d_in[8];
    float* out = (float*)d_out;

    int nnz = in_sizes[0];
    int U   = in_sizes[3] / D;
    int I   = in_sizes[4] / D;
    int N   = U + I;
    int NB  = (N + BROWS - 1) >> BSH;

    // workspace layout
    char* p = (char*)d_ws;
    unsigned short* featb = (unsigned short*)p;  p += (size_t)N * D * 2;            // 38.4 MB
    uint2* epack          = (uint2*)p;           p += (size_t)nnz * 8;              // 38.4 MB
    int* row_start        = (int*)p;             p += (size_t)N * 4;
    int* rend             = (int*)p;             p += (size_t)N * 4;
    float* nsave          = (float*)p;           p += (size_t)N * 4;
    int* bstart           = (int*)p;             p += (size_t)(NB + 1) * 4;
    p = (char*)(((size_t)p + 63) & ~(size_t)63);
    int* bcount           = (int*)p;             p += (size_t)NB * 64;              // padded
    int* bcursor          = (int*)p;             p += (size_t)NB * 64;              // padded

    // temp bucket-grouped edges: reuse featb's space (dead until gemms run).
    uint2* etmp;
    if ((size_t)nnz * 8 <= (size_t)N * D * 2) {
        etmp = (uint2*)featb;
    } else {
        etmp = (uint2*)p;
    }

    int vec_blocks = (N * (D / 4) + 255) / 256;
    int row_blocks = (N + 3) / 4;
    int gu = (U + GR - 1) / GR;
    int gi = (I + GR - 1) / GR;

    copy_raw<<<vec_blocks, 256, 0, stream>>>(ue, ie, out, U, N);

    // ---- build CSR (bucketed, chunked scatter -> per-bucket 2-pass sort) ----
    hipMemsetAsync(bcount, 0, (size_t)NB * 128, stream);   // bcount + bcursor contiguous
    bucket_hist<<<512, 256, 0, stream>>>(rows, bcount, nnz, NB);
    bucket_scan<<<1, 256, 0, stream>>>(bcount, bstart, bcursor, NB);
    chunk_scatter<<<512, 256, 0, stream>>>(rows, cols, vals, bcursor, etmp, nnz, NB);
    bucket_sort2<<<NB, 256, 0, stream>>>(bstart, etmp, epack, row_start, rend, N);

    // ---- layer 0: gemm (bf16 out) -> spmm (leaky + norm into out[128:256), save n) ----
    gemm64<<<gu, 256, 0, stream>>>(ue, D, uw0, featb, nullptr, U);
    gemm64<<<gi, 256, 0, stream>>>(ie, D, vw0, featb + (size_t)U * D, nullptr, I);
    spmm_csr2<<<row_blocks, 256, 0, stream>>>(epack, row_start, rend, featb, out,
                                              nsave, D, N);

    // ---- layer 1: gemm reads normalized out cols * nsave (recovers unnormalized) ----
    gemm64<<<gu, 256, 0, stream>>>(out + D, OUTD, uw1, featb, nsave, U);
    gemm64<<<gi, 256, 0, stream>>>(out + (size_t)U * OUTD + D, OUTD, vw1,
                                   featb + (size_t)U * D, nsave + U, I);
    spmm_csr2<<<row_blocks, 256, 0, stream>>>(epack, row_start, rend, featb, out,
                                              nullptr, 2 * D, N);
}

// Round 7
// 769.659 us; speedup vs baseline: 1.2642x; 1.0267x over previous
//
#include <hip/hip_runtime.h>

#define D 128
#define OUTD 384
#define SLOPE 0.2f
#define BSH 8                  // bucket = row >> 8  (256 rows/bucket)
#define BROWS 256
#define MAXNB 1024

__device__ __forceinline__ unsigned f2bf(float f) {   // round-to-nearest-even bf16
    unsigned u = __float_as_uint(f);
    return (u + 0x7FFFu + ((u >> 16) & 1u)) >> 16;
}

// ---------------- copy raw embeddings into out cols [0,128) ----------------
__global__ __launch_bounds__(256) void copy_raw(const float* __restrict__ ue,
                                                const float* __restrict__ ie,
                                                float* __restrict__ out,
                                                int U, int N) {
    int idx = blockIdx.x * 256 + threadIdx.x;
    int total = N * (D / 4);
    if (idx >= total) return;
    int row = idx >> 5;
    int c4  = (idx & 31) * 4;
    const float* src = (row < U) ? &ue[(size_t)row * D] : &ie[(size_t)(row - U) * D];
    *(float4*)&out[(size_t)row * OUTD + c4] = *(const float4*)&src[c4];
}

// ---------------- dense GEMM: featb[r] = bf16( (rowscale[r] * in[r*pitch]) @ W ) ----------
#define GR 64
__global__ __launch_bounds__(256) void gemm64(const float* __restrict__ in, int pitch,
                                              const float* __restrict__ W,
                                              unsigned short* __restrict__ featb,
                                              const float* __restrict__ rowscale,
                                              int nrows) {
    __shared__ float sIn[GR * D];    // 32 KB
    __shared__ float sW[64 * D];     // 32 KB
    int tid = threadIdx.x;
    int row0 = blockIdx.x * GR;
    int nr = min(GR, nrows - row0);

    for (int i = tid; i < nr * 32; i += 256) {
        int r = i >> 5, c = (i & 31) * 4;
        float4 t = *(const float4*)&in[(size_t)(row0 + r) * pitch + c];
        if (rowscale) {
            float s = rowscale[row0 + r];
            t.x *= s; t.y *= s; t.z *= s; t.w *= s;
        }
        *(float4*)&sIn[r * D + c] = t;
    }

    int cg = tid & 31;
    int rs = tid >> 5;
    int c4 = cg * 4;

    float4 acc[8];
#pragma unroll
    for (int j = 0; j < 8; ++j) acc[j] = make_float4(0.f, 0.f, 0.f, 0.f);

    for (int kh = 0; kh < 2; ++kh) {
        __syncthreads();
        for (int i = tid * 4; i < 64 * D; i += 256 * 4)
            *(float4*)&sW[i] = *(const float4*)&W[kh * 64 * D + i];
        __syncthreads();
#pragma unroll 4
        for (int k = 0; k < 64; ++k) {
            float4 w = *(float4*)&sW[k * D + c4];
#pragma unroll
            for (int j = 0; j < 8; ++j) {
                float av = sIn[(rs * 8 + j) * D + kh * 64 + k];
                acc[j].x += av * w.x;
                acc[j].y += av * w.y;
                acc[j].z += av * w.z;
                acc[j].w += av * w.w;
            }
        }
    }
#pragma unroll
    for (int j = 0; j < 8; ++j) {
        int r = rs * 8 + j;
        if (r < nr) {
            uint2 p;
            p.x = f2bf(acc[j].x) | (f2bf(acc[j].y) << 16);
            p.y = f2bf(acc[j].z) | (f2bf(acc[j].w) << 16);
            *(uint2*)&featb[(size_t)(row0 + r) * D + c4] = p;
        }
    }
}

// ================= bucketed CSR build =================
// bcount/bcursor are padded: one int per 64B line (index b*16)

__global__ __launch_bounds__(256) void bucket_hist(const int* __restrict__ rows,
                                                   int* __restrict__ bcount,
                                                   int nnz, int NB) {
    __shared__ int h[MAXNB];
    if (NB <= MAXNB) {
        for (int i = threadIdx.x; i < NB; i += 256) h[i] = 0;
        __syncthreads();
        int stride = gridDim.x * 256;
        for (int e = blockIdx.x * 256 + threadIdx.x; e < nnz; e += stride)
            atomicAdd(&h[rows[e] >> BSH], 1);
        __syncthreads();
        for (int i = threadIdx.x; i < NB; i += 256)
            if (h[i]) atomicAdd(&bcount[i * 16], h[i]);
    } else {
        int stride = gridDim.x * 256;
        for (int e = blockIdx.x * 256 + threadIdx.x; e < nnz; e += stride)
            atomicAdd(&bcount[(rows[e] >> BSH) * 16], 1);
    }
}

__global__ __launch_bounds__(256) void bucket_scan(const int* __restrict__ bcount,
                                                   int* __restrict__ bstart,
                                                   int* __restrict__ bcursor, int NB) {
    __shared__ int ps[257];
    int tid = threadIdx.x;
    int per = (NB + 255) / 256;
    int lo = tid * per, hi = min(lo + per, NB);
    int sum = 0;
    for (int i = lo; i < hi; ++i) sum += bcount[i * 16];
    ps[tid] = sum;
    __syncthreads();
    if (tid == 0) {
        int acc = 0;
        for (int i = 0; i < 256; ++i) { int t = ps[i]; ps[i] = acc; acc += t; }
        ps[256] = acc;
    }
    __syncthreads();
    int acc = ps[tid];
    for (int i = lo; i < hi; ++i) {
        int c = bcount[i * 16];
        bstart[i] = acc;
        bcursor[i * 16] = acc;
        acc += c;
    }
    if (tid == 255) bstart[NB] = ps[256];
}

// chunked scatter: each block owns a contiguous edge span; per-bucket LDS histogram,
// one chunk reservation atomic per (block,bucket), then contiguous chunk writes.
#define SCT 512
__global__ __launch_bounds__(SCT) void chunk_scatter(const int* __restrict__ rows,
                                                     const int* __restrict__ cols,
                                                     const float* __restrict__ vals,
                                                     int* __restrict__ bcursor,
                                                     uint2* __restrict__ etmp,
                                                     int nnz, int NB) {
    __shared__ int hist[MAXNB];
    int tid  = threadIdx.x;
    int span = (nnz + gridDim.x - 1) / gridDim.x;
    int lo   = blockIdx.x * span;
    int hi   = min(lo + span, nnz);
    if (NB <= MAXNB) {
        for (int i = tid; i < NB; i += SCT) hist[i] = 0;
        __syncthreads();
        for (int e = lo + tid; e < hi; e += SCT)
            atomicAdd(&hist[rows[e] >> BSH], 1);
        __syncthreads();
        for (int i = tid; i < NB; i += SCT) {
            int c = hist[i];
            hist[i] = c ? atomicAdd(&bcursor[i * 16], c) : 0;   // chunk base
        }
        __syncthreads();
        for (int e = lo + tid; e < hi; e += SCT) {
            int r = rows[e];
            int b = r >> BSH;
            int pos = atomicAdd(&hist[b], 1);
            uint2 p;
            p.x = ((unsigned)(r & (BROWS - 1)) << 18) | (unsigned)cols[e];
            p.y = __float_as_uint(vals[e]);
            etmp[pos] = p;
        }
    } else {
        for (int e = lo + tid; e < hi; e += SCT) {
            int r = rows[e];
            int b = r >> BSH;
            int pos = atomicAdd(&bcursor[b * 16], 1);
            uint2 p;
            p.x = ((unsigned)(r & (BROWS - 1)) << 18) | (unsigned)cols[e];
            p.y = __float_as_uint(vals[e]);
            etmp[pos] = p;
        }
    }
}

// per-bucket two-pass row sort: etmp (bucket-grouped) -> epack (row-sorted),
// emits row_start / rend.
#define SRT 1024
__global__ __launch_bounds__(SRT) void bucket_sort2(const int* __restrict__ bstart,
                                                    const uint2* __restrict__ etmp,
                                                    uint2* __restrict__ epack,
                                                    int* __restrict__ row_start,
                                                    int* __restrict__ rend,
                                                    int N) {
    __shared__ int rcnt[BROWS];
    __shared__ int rbase[BROWS];
    __shared__ int wsum[4];
    int b   = blockIdx.x;
    int s   = bstart[b];
    int len = bstart[b + 1] - s;
    int tid = threadIdx.x;
    if (tid < BROWS) rcnt[tid] = 0;
    __syncthreads();
    for (int i = tid; i < len; i += SRT)
        atomicAdd(&rcnt[etmp[s + i].x >> 18], 1);
    __syncthreads();
    if (tid < BROWS) {
        int c = rcnt[tid];
        int lane = tid & 63, wid = tid >> 6;
        int incl = c;
#pragma unroll
        for (int off = 1; off < 64; off <<= 1) {
            int t = __shfl_up(incl, off);
            if (lane >= off) incl += t;
        }
        if (lane == 63) wsum[wid] = incl;
        __syncthreads();
        int woff = 0;
        for (int w = 0; w < wid; ++w) woff += wsum[w];
        int excl = woff + incl - c;
        rbase[tid] = s + excl;
        int row = b * BROWS + tid;
        if (row < N) { row_start[row] = s + excl; rend[row] = s + excl + c; }
    } else {
        __syncthreads();
    }
    __syncthreads();
    for (int i = tid; i < len; i += SRT) {
        uint2 e = etmp[s + i];
        int rl = e.x >> 18;
        int pos = atomicAdd(&rbase[rl], 1);
        uint2 o; o.x = e.x & 0x3FFFFu; o.y = e.y;
        epack[pos] = o;
    }
}

// ================= CSR SpMM v4: wave per row, 4 edges per gather instruction ==========
// Lane (h, j): h = lane>>4 (edge slot), j = lane&15 (dim group: dims [8j, 8j+8)).
// One ep load (dwordx2) + one gather (dwordx4, 16 B) per 4 edges.
#define ACCQ(vbits, g)                                             \
    {                                                              \
        float v = __uint_as_float(vbits);                          \
        acc0.x += v * __uint_as_float((g).x << 16);                \
        acc0.y += v * __uint_as_float((g).x & 0xFFFF0000u);        \
        acc0.z += v * __uint_as_float((g).y << 16);                \
        acc0.w += v * __uint_as_float((g).y & 0xFFFF0000u);        \
        acc1.x += v * __uint_as_float((g).z << 16);                \
        acc1.y += v * __uint_as_float((g).z & 0xFFFF0000u);        \
        acc1.z += v * __uint_as_float((g).w << 16);                \
        acc1.w += v * __uint_as_float((g).w & 0xFFFF0000u);        \
    }

__global__ __launch_bounds__(256) void spmm_csr4(const uint2* __restrict__ ep,
                                                 const int* __restrict__ rstart,
                                                 const int* __restrict__ rend,
                                                 const unsigned short* __restrict__ featb,
                                                 float* __restrict__ out,
                                                 float* __restrict__ nsave,
                                                 int col_off, int N) {
    int row  = blockIdx.x * 4 + (threadIdx.x >> 6);
    if (row >= N) return;
    int lane = threadIdx.x & 63;
    int j = lane & 15;      // dim group
    int h = lane >> 4;      // edge slot
    int s = rstart[row], e = rend[row];

    float4 acc0 = {0.f, 0.f, 0.f, 0.f};
    float4 acc1 = {0.f, 0.f, 0.f, 0.f};
    int i = s;
    for (; i + 8 <= e; i += 8) {
        uint2 eA = ep[i + h];
        uint2 eB = ep[i + 4 + h];
        uint4 gA = *(const uint4*)&featb[(size_t)eA.x * D + j * 8];
        uint4 gB = *(const uint4*)&featb[(size_t)eB.x * D + j * 8];
        ACCQ(eA.y, gA);
        ACCQ(eB.y, gB);
    }
    for (; i < e; i += 4) {
        int idx = i + h;
        uint2 ev = make_uint2(0u, 0u);          // col 0 / val 0: harmless dummy
        if (idx < e) ev = ep[idx];
        uint4 g = *(const uint4*)&featb[(size_t)ev.x * D + j * 8];
        ACCQ(ev.y, g);
    }

    // combine the four edge slots (xor over lane bits 4 and 5)
#pragma unroll
    for (int m = 16; m <= 32; m <<= 1) {
        acc0.x += __shfl_xor(acc0.x, m);
        acc0.y += __shfl_xor(acc0.y, m);
        acc0.z += __shfl_xor(acc0.z, m);
        acc0.w += __shfl_xor(acc0.w, m);
        acc1.x += __shfl_xor(acc1.x, m);
        acc1.y += __shfl_xor(acc1.y, m);
        acc1.z += __shfl_xor(acc1.z, m);
        acc1.w += __shfl_xor(acc1.w, m);
    }

    // leaky relu
    acc0.x = (acc0.x > 0.f) ? acc0.x : SLOPE * acc0.x;
    acc0.y = (acc0.y > 0.f) ? acc0.y : SLOPE * acc0.y;
    acc0.z = (acc0.z > 0.f) ? acc0.z : SLOPE * acc0.z;
    acc0.w = (acc0.w > 0.f) ? acc0.w : SLOPE * acc0.w;
    acc1.x = (acc1.x > 0.f) ? acc1.x : SLOPE * acc1.x;
    acc1.y = (acc1.y > 0.f) ? acc1.y : SLOPE * acc1.y;
    acc1.z = (acc1.z > 0.f) ? acc1.z : SLOPE * acc1.z;
    acc1.w = (acc1.w > 0.f) ? acc1.w : SLOPE * acc1.w;

    // L2 norm over 128 cols (each 16-lane group holds the full row after combine)
    float ss = acc0.x * acc0.x + acc0.y * acc0.y + acc0.z * acc0.z + acc0.w * acc0.w
             + acc1.x * acc1.x + acc1.y * acc1.y + acc1.z * acc1.z + acc1.w * acc1.w;
#pragma unroll
    for (int m = 8; m >= 1; m >>= 1) ss += __shfl_xor(ss, m);
    float nm = fmaxf(sqrtf(ss), 1e-12f);
    float sc = 1.0f / nm;

    if (nsave && lane == 0) nsave[row] = nm;
    if (h == 0) {
        float* dst = &out[(size_t)row * OUTD + col_off + j * 8];
        float4 o0 = {acc0.x * sc, acc0.y * sc, acc0.z * sc, acc0.w * sc};
        float4 o1 = {acc1.x * sc, acc1.y * sc, acc1.z * sc, acc1.w * sc};
        *(float4*)&dst[0] = o0;
        *(float4*)&dst[4] = o1;
    }
}

extern "C" void kernel_launch(void* const* d_in, const int* in_sizes, int n_in,
                              void* d_out, int out_size, void* d_ws, size_t ws_size,
                              hipStream_t stream) {
    const int*   rows = (const int*)d_in[0];
    const int*   cols = (const int*)d_in[1];
    const float* vals = (const float*)d_in[2];
    const float* ue   = (const float*)d_in[3];
    const float* ie   = (const float*)d_in[4];
    const float* uw0  = (const float*)d_in[5];
    const float* vw0  = (const float*)d_in[6];
    const float* uw1  = (const float*)d_in[7];
    const float* vw1  = (const float*)d_in[8];
    float* out = (float*)d_out;

    int nnz = in_sizes[0];
    int U   = in_sizes[3] / D;
    int I   = in_sizes[4] / D;
    int N   = U + I;
    int NB  = (N + BROWS - 1) >> BSH;

    // workspace layout
    char* p = (char*)d_ws;
    unsigned short* featb = (unsigned short*)p;  p += (size_t)N * D * 2;            // 38.4 MB
    uint2* epack          = (uint2*)p;           p += (size_t)nnz * 8;              // 38.4 MB
    int* row_start        = (int*)p;             p += (size_t)N * 4;
    int* rend             = (int*)p;             p += (size_t)N * 4;
    float* nsave          = (float*)p;           p += (size_t)N * 4;
    int* bstart           = (int*)p;             p += (size_t)(NB + 1) * 4;
    p = (char*)(((size_t)p + 63) & ~(size_t)63);
    int* bcount           = (int*)p;             p += (size_t)NB * 64;              // padded
    int* bcursor          = (int*)p;             p += (size_t)NB * 64;              // padded

    // temp bucket-grouped edges: reuse featb's space (dead until gemms run).
    uint2* etmp;
    if ((size_t)nnz * 8 <= (size_t)N * D * 2) {
        etmp = (uint2*)featb;
    } else {
        etmp = (uint2*)p;
    }

    int vec_blocks = (N * (D / 4) + 255) / 256;
    int row_blocks = (N + 3) / 4;
    int gu = (U + GR - 1) / GR;
    int gi = (I + GR - 1) / GR;

    copy_raw<<<vec_blocks, 256, 0, stream>>>(ue, ie, out, U, N);

    // ---- build CSR (bucketed, chunked scatter -> per-bucket 2-pass sort) ----
    hipMemsetAsync(bcount, 0, (size_t)NB * 128, stream);   // bcount + bcursor contiguous
    bucket_hist<<<512, 256, 0, stream>>>(rows, bcount, nnz, NB);
    bucket_scan<<<1, 256, 0, stream>>>(bcount, bstart, bcursor, NB);
    chunk_scatter<<<512, SCT, 0, stream>>>(rows, cols, vals, bcursor, etmp, nnz, NB);
    bucket_sort2<<<NB, SRT, 0, stream>>>(bstart, etmp, epack, row_start, rend, N);

    // ---- layer 0: gemm (bf16 out) -> spmm (leaky + norm into out[128:256), save n) ----
    gemm64<<<gu, 256, 0, stream>>>(ue, D, uw0, featb, nullptr, U);
    gemm64<<<gi, 256, 0, stream>>>(ie, D, vw0, featb + (size_t)U * D, nullptr, I);
    spmm_csr4<<<row_blocks, 256, 0, stream>>>(epack, row_start, rend, featb, out,
                                              nsave, D, N);

    // ---- layer 1: gemm reads normalized out cols * nsave (recovers unnormalized) ----
    gemm64<<<gu, 256, 0, stream>>>(out + D, OUTD, uw1, featb, nsave, U);
    gemm64<<<gi, 256, 0, stream>>>(out + (size_t)U * OUTD + D, OUTD, vw1,
                                   featb + (size_t)U * D, nsave + U, I);
    spmm_csr4<<<row_blocks, 256, 0, stream>>>(epack, row_start, rend, featb, out,
                                              nullptr, 2 * D, N);
}

// Round 8
// 692.616 us; speedup vs baseline: 1.4048x; 1.1112x over previous
//
#include <hip/hip_runtime.h>

#define D 128
#define OUTD 384
#define SLOPE 0.2f
#define BSH 8                  // bucket = row >> 8  (256 rows/bucket)
#define BROWS 256
#define MAXNB 1024

typedef __attribute__((ext_vector_type(8))) short bf16x8;
typedef __attribute__((ext_vector_type(4))) float f32x4;

__device__ __forceinline__ unsigned f2bf(float f) {   // round-to-nearest-even bf16
    unsigned u = __float_as_uint(f);
    return (u + 0x7FFFu + ((u >> 16) & 1u)) >> 16;
}

// ---------------- copy raw embeddings into out cols [0,128) ----------------
__global__ __launch_bounds__(256) void copy_raw(const float* __restrict__ ue,
                                                const float* __restrict__ ie,
                                                float* __restrict__ out,
                                                int U, int N) {
    int idx = blockIdx.x * 256 + threadIdx.x;
    int total = N * (D / 4);
    if (idx >= total) return;
    int row = idx >> 5;
    int c4  = (idx & 31) * 4;
    const float* src = (row < U) ? &ue[(size_t)row * D] : &ie[(size_t)(row - U) * D];
    *(float4*)&out[(size_t)row * OUTD + c4] = *(const float4*)&src[c4];
}

// ---------------- MFMA GEMM: featb[r] = bf16( (rowscale[r]*in[r*pitch]) @ W ) -------------
// 64 rows/block, 256 thr = 4 waves; wave w owns rows 16w..16w+15, all 128 cols.
// LDS: A bf16 [64][136], Wt bf16 [128][136] (W transposed so B-frag is contiguous).
#define GR 64
#define APAD 136
__global__ __launch_bounds__(256) void gemm_mfma(const float* __restrict__ in, int pitch,
                                                 const float* __restrict__ W,
                                                 unsigned short* __restrict__ featb,
                                                 const float* __restrict__ rowscale,
                                                 int nrows) {
    __shared__ unsigned short sA[GR * APAD];     // 17.4 KB
    __shared__ unsigned short sW[128 * APAD];    // 34.8 KB
    int tid = threadIdx.x;
    int row0 = blockIdx.x * GR;
    int nr = min(GR, nrows - row0);

    // stage A (bf16, rowscaled, zero-padded rows >= nr)
    for (int i = tid; i < GR * 32; i += 256) {
        int r = i >> 5, c4 = (i & 31) * 4;
        unsigned lo = 0, hi = 0;
        if (r < nr) {
            float4 t = *(const float4*)&in[(size_t)(row0 + r) * pitch + c4];
            if (rowscale) {
                float s = rowscale[row0 + r];
                t.x *= s; t.y *= s; t.z *= s; t.w *= s;
            }
            lo = f2bf(t.x) | (f2bf(t.y) << 16);
            hi = f2bf(t.z) | (f2bf(t.w) << 16);
        }
        uint2 pk = {lo, hi};
        *(uint2*)&sA[r * APAD + c4] = pk;
    }
    // stage W transposed: sW[n][k] = bf16(W[k][n])
    for (int i = tid; i < 128 * 32; i += 256) {
        int k = i >> 5, c4 = (i & 31) * 4;
        float4 t = *(const float4*)&W[(size_t)k * 128 + c4];
        sW[(c4 + 0) * APAD + k] = (unsigned short)f2bf(t.x);
        sW[(c4 + 1) * APAD + k] = (unsigned short)f2bf(t.y);
        sW[(c4 + 2) * APAD + k] = (unsigned short)f2bf(t.z);
        sW[(c4 + 3) * APAD + k] = (unsigned short)f2bf(t.w);
    }
    __syncthreads();

    int l  = tid & 63;
    int w  = tid >> 6;
    int lr = l & 15;             // A-row / B-col within tile
    int lk = (l >> 4) * 8;       // k sub-offset

    f32x4 acc[8];
#pragma unroll
    for (int t = 0; t < 8; ++t) acc[t] = (f32x4){0.f, 0.f, 0.f, 0.f};

#pragma unroll
    for (int k0 = 0; k0 < 128; k0 += 32) {
        bf16x8 af = *(const bf16x8*)&sA[(16 * w + lr) * APAD + k0 + lk];
#pragma unroll
        for (int t = 0; t < 8; ++t) {
            bf16x8 bf = *(const bf16x8*)&sW[(t * 16 + lr) * APAD + k0 + lk];
            acc[t] = __builtin_amdgcn_mfma_f32_16x16x32_bf16(af, bf, acc[t], 0, 0, 0);
        }
    }

    // D layout: col = lane&15, row = (lane>>4)*4 + reg
    int rbase = 16 * w + (l >> 4) * 4;
#pragma unroll
    for (int t = 0; t < 8; ++t) {
#pragma unroll
        for (int q = 0; q < 4; ++q) {
            int r = rbase + q;
            if (r < nr)
                featb[(size_t)(row0 + r) * D + t * 16 + lr] = (unsigned short)f2bf(acc[t][q]);
        }
    }
}

// ================= bucketed CSR build =================
// bcount/bcursor are padded: one int per 64B line (index b*16)

__global__ __launch_bounds__(256) void bucket_hist(const int* __restrict__ rows,
                                                   int* __restrict__ bcount,
                                                   int nnz, int NB) {
    __shared__ int h[MAXNB];
    if (NB <= MAXNB) {
        for (int i = threadIdx.x; i < NB; i += 256) h[i] = 0;
        __syncthreads();
        int stride = gridDim.x * 256;
        for (int e = blockIdx.x * 256 + threadIdx.x; e < nnz; e += stride)
            atomicAdd(&h[rows[e] >> BSH], 1);
        __syncthreads();
        for (int i = threadIdx.x; i < NB; i += 256)
            if (h[i]) atomicAdd(&bcount[i * 16], h[i]);
    } else {
        int stride = gridDim.x * 256;
        for (int e = blockIdx.x * 256 + threadIdx.x; e < nnz; e += stride)
            atomicAdd(&bcount[(rows[e] >> BSH) * 16], 1);
    }
}

__global__ __launch_bounds__(256) void bucket_scan(const int* __restrict__ bcount,
                                                   int* __restrict__ bstart,
                                                   int* __restrict__ bcursor, int NB) {
    __shared__ int ps[257];
    int tid = threadIdx.x;
    int per = (NB + 255) / 256;
    int lo = tid * per, hi = min(lo + per, NB);
    int sum = 0;
    for (int i = lo; i < hi; ++i) sum += bcount[i * 16];
    ps[tid] = sum;
    __syncthreads();
    if (tid == 0) {
        int acc = 0;
        for (int i = 0; i < 256; ++i) { int t = ps[i]; ps[i] = acc; acc += t; }
        ps[256] = acc;
    }
    __syncthreads();
    int acc = ps[tid];
    for (int i = lo; i < hi; ++i) {
        int c = bcount[i * 16];
        bstart[i] = acc;
        bcursor[i * 16] = acc;
        acc += c;
    }
    if (tid == 255) bstart[NB] = ps[256];
}

// chunked scatter: each block owns a contiguous edge span; per-bucket LDS histogram,
// one chunk reservation atomic per (block,bucket), then contiguous chunk writes.
#define SCT 512
__global__ __launch_bounds__(SCT) void chunk_scatter(const int* __restrict__ rows,
                                                     const int* __restrict__ cols,
                                                     const float* __restrict__ vals,
                                                     int* __restrict__ bcursor,
                                                     uint2* __restrict__ etmp,
                                                     int nnz, int NB) {
    __shared__ int hist[MAXNB];
    int tid  = threadIdx.x;
    int span = (nnz + gridDim.x - 1) / gridDim.x;
    int lo   = blockIdx.x * span;
    int hi   = min(lo + span, nnz);
    if (NB <= MAXNB) {
        for (int i = tid; i < NB; i += SCT) hist[i] = 0;
        __syncthreads();
        for (int e = lo + tid; e < hi; e += SCT)
            atomicAdd(&hist[rows[e] >> BSH], 1);
        __syncthreads();
        for (int i = tid; i < NB; i += SCT) {
            int c = hist[i];
            hist[i] = c ? atomicAdd(&bcursor[i * 16], c) : 0;   // chunk base
        }
        __syncthreads();
        for (int e = lo + tid; e < hi; e += SCT) {
            int r = rows[e];
            int b = r >> BSH;
            int pos = atomicAdd(&hist[b], 1);
            uint2 p;
            p.x = ((unsigned)(r & (BROWS - 1)) << 18) | (unsigned)cols[e];
            p.y = __float_as_uint(vals[e]);
            etmp[pos] = p;
        }
    } else {
        for (int e = lo + tid; e < hi; e += SCT) {
            int r = rows[e];
            int b = r >> BSH;
            int pos = atomicAdd(&bcursor[b * 16], 1);
            uint2 p;
            p.x = ((unsigned)(r & (BROWS - 1)) << 18) | (unsigned)cols[e];
            p.y = __float_as_uint(vals[e]);
            etmp[pos] = p;
        }
    }
}

// per-bucket two-pass row sort: etmp (bucket-grouped) -> epack (row-sorted),
// emits row_start / rend.
#define SRT 1024
__global__ __launch_bounds__(SRT) void bucket_sort2(const int* __restrict__ bstart,
                                                    const uint2* __restrict__ etmp,
                                                    uint2* __restrict__ epack,
                                                    int* __restrict__ row_start,
                                                    int* __restrict__ rend,
                                                    int N) {
    __shared__ int rcnt[BROWS];
    __shared__ int rbase[BROWS];
    __shared__ int wsum[4];
    int b   = blockIdx.x;
    int s   = bstart[b];
    int len = bstart[b + 1] - s;
    int tid = threadIdx.x;
    if (tid < BROWS) rcnt[tid] = 0;
    __syncthreads();
    for (int i = tid; i < len; i += SRT)
        atomicAdd(&rcnt[etmp[s + i].x >> 18], 1);
    __syncthreads();
    if (tid < BROWS) {
        int c = rcnt[tid];
        int lane = tid & 63, wid = tid >> 6;
        int incl = c;
#pragma unroll
        for (int off = 1; off < 64; off <<= 1) {
            int t = __shfl_up(incl, off);
            if (lane >= off) incl += t;
        }
        if (lane == 63) wsum[wid] = incl;
        __syncthreads();
        int woff = 0;
        for (int w = 0; w < wid; ++w) woff += wsum[w];
        int excl = woff + incl - c;
        rbase[tid] = s + excl;
        int row = b * BROWS + tid;
        if (row < N) { row_start[row] = s + excl; rend[row] = s + excl + c; }
    } else {
        __syncthreads();
    }
    __syncthreads();
    for (int i = tid; i < len; i += SRT) {
        uint2 e = etmp[s + i];
        int rl = e.x >> 18;
        int pos = atomicAdd(&rbase[rl], 1);
        uint2 o; o.x = e.x & 0x3FFFFu; o.y = e.y;
        epack[pos] = o;
    }
}

// ================= CSR SpMM v4: wave per row, 4 edges per gather instruction ==========
// Lane (h, j): h = lane>>4 (edge slot), j = lane&15 (dim group: dims [8j, 8j+8)).
#define ACCQ(vbits, g)                                             \
    {                                                              \
        float v = __uint_as_float(vbits);                          \
        acc0.x += v * __uint_as_float((g).x << 16);                \
        acc0.y += v * __uint_as_float((g).x & 0xFFFF0000u);        \
        acc0.z += v * __uint_as_float((g).y << 16);                \
        acc0.w += v * __uint_as_float((g).y & 0xFFFF0000u);        \
        acc1.x += v * __uint_as_float((g).z << 16);                \
        acc1.y += v * __uint_as_float((g).z & 0xFFFF0000u);        \
        acc1.z += v * __uint_as_float((g).w << 16);                \
        acc1.w += v * __uint_as_float((g).w & 0xFFFF0000u);        \
    }

__global__ __launch_bounds__(256) void spmm_csr4(const uint2* __restrict__ ep,
                                                 const int* __restrict__ rstart,
                                                 const int* __restrict__ rend,
                                                 const unsigned short* __restrict__ featb,
                                                 float* __restrict__ out,
                                                 float* __restrict__ nsave,
                                                 int col_off, int N) {
    int row  = blockIdx.x * 4 + (threadIdx.x >> 6);
    if (row >= N) return;
    int lane = threadIdx.x & 63;
    int j = lane & 15;      // dim group
    int h = lane >> 4;      // edge slot
    int s = rstart[row], e = rend[row];

    float4 acc0 = {0.f, 0.f, 0.f, 0.f};
    float4 acc1 = {0.f, 0.f, 0.f, 0.f};
    int i = s;
    for (; i + 16 <= e; i += 16) {
        uint2 eA = ep[i + h];
        uint2 eB = ep[i + 4 + h];
        uint2 eC = ep[i + 8 + h];
        uint2 eD = ep[i + 12 + h];
        uint4 gA = *(const uint4*)&featb[(size_t)eA.x * D + j * 8];
        uint4 gB = *(const uint4*)&featb[(size_t)eB.x * D + j * 8];
        uint4 gC = *(const uint4*)&featb[(size_t)eC.x * D + j * 8];
        uint4 gD = *(const uint4*)&featb[(size_t)eD.x * D + j * 8];
        ACCQ(eA.y, gA);
        ACCQ(eB.y, gB);
        ACCQ(eC.y, gC);
        ACCQ(eD.y, gD);
    }
    for (; i + 8 <= e; i += 8) {
        uint2 eA = ep[i + h];
        uint2 eB = ep[i + 4 + h];
        uint4 gA = *(const uint4*)&featb[(size_t)eA.x * D + j * 8];
        uint4 gB = *(const uint4*)&featb[(size_t)eB.x * D + j * 8];
        ACCQ(eA.y, gA);
        ACCQ(eB.y, gB);
    }
    for (; i < e; i += 4) {
        int idx = i + h;
        uint2 ev = make_uint2(0u, 0u);          // col 0 / val 0: harmless dummy
        if (idx < e) ev = ep[idx];
        uint4 g = *(const uint4*)&featb[(size_t)ev.x * D + j * 8];
        ACCQ(ev.y, g);
    }

    // combine the four edge slots (xor over lane bits 4 and 5)
#pragma unroll
    for (int m = 16; m <= 32; m <<= 1) {
        acc0.x += __shfl_xor(acc0.x, m);
        acc0.y += __shfl_xor(acc0.y, m);
        acc0.z += __shfl_xor(acc0.z, m);
        acc0.w += __shfl_xor(acc0.w, m);
        acc1.x += __shfl_xor(acc1.x, m);
        acc1.y += __shfl_xor(acc1.y, m);
        acc1.z += __shfl_xor(acc1.z, m);
        acc1.w += __shfl_xor(acc1.w, m);
    }

    // leaky relu
    acc0.x = (acc0.x > 0.f) ? acc0.x : SLOPE * acc0.x;
    acc0.y = (acc0.y > 0.f) ? acc0.y : SLOPE * acc0.y;
    acc0.z = (acc0.z > 0.f) ? acc0.z : SLOPE * acc0.z;
    acc0.w = (acc0.w > 0.f) ? acc0.w : SLOPE * acc0.w;
    acc1.x = (acc1.x > 0.f) ? acc1.x : SLOPE * acc1.x;
    acc1.y = (acc1.y > 0.f) ? acc1.y : SLOPE * acc1.y;
    acc1.z = (acc1.z > 0.f) ? acc1.z : SLOPE * acc1.z;
    acc1.w = (acc1.w > 0.f) ? acc1.w : SLOPE * acc1.w;

    // L2 norm over 128 cols (each 16-lane group holds the full row after combine)
    float ss = acc0.x * acc0.x + acc0.y * acc0.y + acc0.z * acc0.z + acc0.w * acc0.w
             + acc1.x * acc1.x + acc1.y * acc1.y + acc1.z * acc1.z + acc1.w * acc1.w;
#pragma unroll
    for (int m = 8; m >= 1; m >>= 1) ss += __shfl_xor(ss, m);
    float nm = fmaxf(sqrtf(ss), 1e-12f);
    float sc = 1.0f / nm;

    if (nsave && lane == 0) nsave[row] = nm;
    if (h == 0) {
        float* dst = &out[(size_t)row * OUTD + col_off + j * 8];
        float4 o0 = {acc0.x * sc, acc0.y * sc, acc0.z * sc, acc0.w * sc};
        float4 o1 = {acc1.x * sc, acc1.y * sc, acc1.z * sc, acc1.w * sc};
        *(float4*)&dst[0] = o0;
        *(float4*)&dst[4] = o1;
    }
}

extern "C" void kernel_launch(void* const* d_in, const int* in_sizes, int n_in,
                              void* d_out, int out_size, void* d_ws, size_t ws_size,
                              hipStream_t stream) {
    const int*   rows = (const int*)d_in[0];
    const int*   cols = (const int*)d_in[1];
    const float* vals = (const float*)d_in[2];
    const float* ue   = (const float*)d_in[3];
    const float* ie   = (const float*)d_in[4];
    const float* uw0  = (const float*)d_in[5];
    const float* vw0  = (const float*)d_in[6];
    const float* uw1  = (const float*)d_in[7];
    const float* vw1  = (const float*)d_in[8];
    float* out = (float*)d_out;

    int nnz = in_sizes[0];
    int U   = in_sizes[3] / D;
    int I   = in_sizes[4] / D;
    int N   = U + I;
    int NB  = (N + BROWS - 1) >> BSH;

    // workspace layout
    char* p = (char*)d_ws;
    unsigned short* featb = (unsigned short*)p;  p += (size_t)N * D * 2;            // 38.4 MB
    uint2* epack          = (uint2*)p;           p += (size_t)nnz * 8;              // 38.4 MB
    int* row_start        = (int*)p;             p += (size_t)N * 4;
    int* rend             = (int*)p;             p += (size_t)N * 4;
    float* nsave          = (float*)p;           p += (size_t)N * 4;
    int* bstart           = (int*)p;             p += (size_t)(NB + 1) * 4;
    p = (char*)(((size_t)p + 63) & ~(size_t)63);
    int* bcount           = (int*)p;             p += (size_t)NB * 64;              // padded
    int* bcursor          = (int*)p;             p += (size_t)NB * 64;              // padded

    // temp bucket-grouped edges: reuse featb's space (dead until gemms run).
    uint2* etmp;
    if ((size_t)nnz * 8 <= (size_t)N * D * 2) {
        etmp = (uint2*)featb;
    } else {
        etmp = (uint2*)p;
    }

    int vec_blocks = (N * (D / 4) + 255) / 256;
    int row_blocks = (N + 3) / 4;
    int gu = (U + GR - 1) / GR;
    int gi = (I + GR - 1) / GR;

    copy_raw<<<vec_blocks, 256, 0, stream>>>(ue, ie, out, U, N);

    // ---- build CSR (bucketed, chunked scatter -> per-bucket 2-pass sort) ----
    hipMemsetAsync(bcount, 0, (size_t)NB * 128, stream);   // bcount + bcursor contiguous
    bucket_hist<<<512, 256, 0, stream>>>(rows, bcount, nnz, NB);
    bucket_scan<<<1, 256, 0, stream>>>(bcount, bstart, bcursor, NB);
    chunk_scatter<<<512, SCT, 0, stream>>>(rows, cols, vals, bcursor, etmp, nnz, NB);
    bucket_sort2<<<NB, SRT, 0, stream>>>(bstart, etmp, epack, row_start, rend, N);

    // ---- layer 0: mfma gemm (bf16 out) -> spmm (leaky + norm into out[128:256), save n)
    gemm_mfma<<<gu, 256, 0, stream>>>(ue, D, uw0, featb, nullptr, U);
    gemm_mfma<<<gi, 256, 0, stream>>>(ie, D, vw0, featb + (size_t)U * D, nullptr, I);
    spmm_csr4<<<row_blocks, 256, 0, stream>>>(epack, row_start, rend, featb, out,
                                              nsave, D, N);

    // ---- layer 1: gemm reads normalized out cols * nsave (recovers unnormalized) ----
    gemm_mfma<<<gu, 256, 0, stream>>>(out + D, OUTD, uw1, featb, nsave, U);
    gemm_mfma<<<gi, 256, 0, stream>>>(out + (size_t)U * OUTD + D, OUTD, vw1,
                                      featb + (size_t)U * D, nsave + U, I);
    spmm_csr4<<<row_blocks, 256, 0, stream>>>(epack, row_start, rend, featb, out,
                                              nullptr, 2 * D, N);
}